// Round 4
// baseline (623.695 us; speedup 1.0000x reference)
//
#include <hip/hip_runtime.h>
#include <hip/hip_bf16.h>

typedef __hip_bfloat16 bf16;

#define NATOMS 20000
#define NEDGES 640000
#define FD 128
#define F3 384
#define NR 20
#define APB 8

// All reference dtypes are float32: inputs are const float*, output is float*.
// (Rounds 1-3 failure analysis: round-1 NaN = f32 inputs misread as bf16;
//  rounds 2/3 frozen output-1 error 454.0 = f32 output half-written because
//  we wrote bf16. The harness's "(bf16,...)" label is hardcoded regardless
//  of dtype — red herring.)

// ---------------------------------------------------------------------------
// CSR build: histogram -> exclusive scan -> scatter edge ids by destination.
// ---------------------------------------------------------------------------
__global__ __launch_bounds__(256) void hist_kernel(const int* __restrict__ eidx,
                                                   int* __restrict__ cnt) {
  const int e = blockIdx.x * 256 + threadIdx.x;
  if (e < NEDGES) atomicAdd(&cnt[eidx[e]], 1);
}

__global__ __launch_bounds__(512) void scan_kernel(const int* __restrict__ cnt,
                                                   int* __restrict__ off) {
  __shared__ int part[512];
  const int t = threadIdx.x;
  const int CH = (NATOMS + 511) / 512;   // 40
  const int base = t * CH;
  int s = 0;
  for (int k = 0; k < CH; ++k) {
    const int idx = base + k;
    if (idx < NATOMS) s += cnt[idx];
  }
  part[t] = s;
  __syncthreads();
  if (t == 0) {
    int run = 0;
    for (int i = 0; i < 512; ++i) { const int tmp = part[i]; part[i] = run; run += tmp; }
    off[NATOMS] = run;
  }
  __syncthreads();
  int run = part[t];
  for (int k = 0; k < CH; ++k) {
    const int idx = base + k;
    if (idx < NATOMS) { off[idx] = run; run += cnt[idx]; }
  }
}

__global__ __launch_bounds__(256) void scatter_kernel(const int* __restrict__ eidx,
                                                      int* __restrict__ cursor,
                                                      int* __restrict__ sorted) {
  const int e = blockIdx.x * 256 + threadIdx.x;
  if (e < NEDGES) {
    const int pos = atomicAdd(&cursor[eidx[e]], 1);
    sorted[pos] = e;
  }
}

// ---------------------------------------------------------------------------
// Phase 1: x = silu(q @ W1 + b1) @ W2 + b2  -> bf16 x[N,384] in workspace.
// One 128-thread block handles APB atoms; weights re-read per block (L2-hot).
// ---------------------------------------------------------------------------
__global__ __launch_bounds__(128) void mlp_kernel(
    const float* __restrict__ q, const float* __restrict__ W1, const float* __restrict__ b1,
    const float* __restrict__ W2, const float* __restrict__ b2v, bf16* __restrict__ x)
{
  __shared__ float qL[APB][FD];
  __shared__ float hL[APB][FD];
  const int t = threadIdx.x;
  const int a0 = blockIdx.x * APB;   // NATOMS % APB == 0

  #pragma unroll
  for (int a = 0; a < APB; ++a) qL[a][t] = q[(size_t)(a0 + a) * FD + t];
  __syncthreads();

  float hacc[APB];
  const float bb1 = b1[t];
  #pragma unroll
  for (int a = 0; a < APB; ++a) hacc[a] = bb1;

  for (int i = 0; i < FD; ++i) {
    const float w = W1[(size_t)i * FD + t];      // coalesced across t
    #pragma unroll
    for (int a = 0; a < APB; ++a) hacc[a] += qL[a][i] * w;   // LDS broadcast
  }
  #pragma unroll
  for (int a = 0; a < APB; ++a) hL[a][t] = hacc[a] / (1.f + __expf(-hacc[a]));
  __syncthreads();

  float x0[APB], x1[APB], x2[APB];
  const float c0 = b2v[t], c1 = b2v[FD + t], c2 = b2v[2 * FD + t];
  #pragma unroll
  for (int a = 0; a < APB; ++a) { x0[a] = c0; x1[a] = c1; x2[a] = c2; }

  for (int i = 0; i < FD; ++i) {
    const float w0 = W2[(size_t)i * F3 + t];
    const float w1 = W2[(size_t)i * F3 + FD + t];
    const float w2 = W2[(size_t)i * F3 + 2 * FD + t];
    #pragma unroll
    for (int a = 0; a < APB; ++a) {
      const float hv = hL[a][i];
      x0[a] += hv * w0; x1[a] += hv * w1; x2[a] += hv * w2;
    }
  }
  #pragma unroll
  for (int a = 0; a < APB; ++a) {
    const int n = a0 + a;
    x[(size_t)n * F3 + t]          = __float2bfloat16(x0[a]);
    x[(size_t)n * F3 + FD + t]     = __float2bfloat16(x1[a]);
    x[(size_t)n * F3 + 2 * FD + t] = __float2bfloat16(x2[a]);
  }
}

// ---------------------------------------------------------------------------
// Phase 2 (fused finalize): one block per destination atom. Walk CSR edges,
// accumulate in fp32 registers, write out = f32(q+dq) ++ f32(mu+dmu).
// Wf slices for thread t are edge-invariant -> 60 registers. sin(n*theta)
// via Chebyshev recurrence: one __sincosf per edge; cos doubles as envelope.
// ---------------------------------------------------------------------------
__global__ __launch_bounds__(128) void gather_kernel(
    const float* __restrict__ q, const float* __restrict__ mu, const bf16* __restrict__ x,
    const int* __restrict__ eidx, const float* __restrict__ ew,
    const float* __restrict__ Wf, const float* __restrict__ bfv,
    const int* __restrict__ off, const int* __restrict__ sorted,
    float* __restrict__ out)
{
  const int t = threadIdx.x;
  const int i = blockIdx.x;

  float wf0[NR], wf1[NR], wf2[NR];
  #pragma unroll
  for (int r = 0; r < NR; ++r) {
    wf0[r] = Wf[(size_t)r * F3 + t];
    wf1[r] = Wf[(size_t)r * F3 + FD + t];
    wf2[r] = Wf[(size_t)r * F3 + 2 * FD + t];
  }
  const float bf0 = bfv[t];
  const float bf1 = bfv[FD + t];
  const float bf2 = bfv[2 * FD + t];

  float accq = 0.f, acc0 = 0.f, acc1 = 0.f, acc2 = 0.f;
  const int beg = off[i], end = off[i + 1];

  for (int p = beg; p < end; ++p) {
    const int e = sorted[p];              // block-uniform
    const int j = eidx[NEDGES + e];       // source atom
    const float w0 = ew[(size_t)e * 3 + 0];
    const float w1 = ew[(size_t)e * 3 + 1];
    const float w2 = ew[(size_t)e * 3 + 2];
    const float d = sqrtf(w0 * w0 + w1 * w1 + w2 * w2);
    const float invd = 1.f / d;
    float s1, c1;
    __sincosf(d * 0.628318530717958f, &s1, &c1);   // theta = pi*d/5
    const float env = (d < 5.0f) ? 0.5f * (c1 + 1.f) : 0.f;

    // filter[c] = (sum_r sin((r+1)theta)/d * Wf[r,c] + bf[c]) * env
    float f0 = bf0, f1 = bf1, f2 = bf2;
    float sprev = 0.f, scur = s1;
    const float twoc = 2.f * c1;
    #pragma unroll
    for (int r = 0; r < NR; ++r) {
      const float b = scur * invd;
      f0 += b * wf0[r];
      f1 += b * wf1[r];
      f2 += b * wf2[r];
      const float snext = twoc * scur - sprev;
      sprev = scur; scur = snext;
    }
    f0 *= env; f1 *= env; f2 *= env;

    const bf16* xj = x + (size_t)j * F3;
    const float dq    = f0 * __bfloat162float(xj[t]);
    const float dmuR  = f1 * __bfloat162float(xj[FD + t]);
    const float dmumu = f2 * __bfloat162float(xj[2 * FD + t]);

    accq += dq;
    const float dir0 = w0 * invd, dir1 = w1 * invd, dir2 = w2 * invd;
    const size_t mj = (size_t)j * F3;
    acc0 += dmuR * dir0 + dmumu * mu[mj + t];
    acc1 += dmuR * dir1 + dmumu * mu[mj + FD + t];
    acc2 += dmuR * dir2 + dmumu * mu[mj + 2 * FD + t];
  }

  const size_t NQ = (size_t)NATOMS * FD;
  out[(size_t)i * FD + t] = q[(size_t)i * FD + t] + accq;
  const size_t mi = (size_t)i * F3;
  out[NQ + mi + t]          = mu[mi + t] + acc0;
  out[NQ + mi + FD + t]     = mu[mi + FD + t] + acc1;
  out[NQ + mi + 2 * FD + t] = mu[mi + 2 * FD + t] + acc2;
}

extern "C" void kernel_launch(void* const* d_in, const int* in_sizes, int n_in,
                              void* d_out, int out_size, void* d_ws, size_t ws_size,
                              hipStream_t stream) {
  const float* q   = (const float*)d_in[0];
  const float* mu  = (const float*)d_in[1];
  const int*   eix = (const int*)d_in[2];
  const float* ew  = (const float*)d_in[3];
  const float* W1  = (const float*)d_in[4];
  const float* b1  = (const float*)d_in[5];
  const float* W2  = (const float*)d_in[6];
  const float* b2v = (const float*)d_in[7];
  const float* Wf  = (const float*)d_in[8];
  const float* bfv = (const float*)d_in[9];
  float* out = (float*)d_out;

  // Workspace (18.2 MB): [x bf16 N*384 | sorted int E | off int N+1 | cnt N | cursor N]
  char* w = (char*)d_ws;
  bf16* x      = (bf16*)w;   w += (size_t)NATOMS * F3 * sizeof(bf16);
  int*  sorted = (int*)w;    w += (size_t)NEDGES * sizeof(int);
  int*  off    = (int*)w;    w += (size_t)(NATOMS + 1) * sizeof(int);
  int*  cnt    = (int*)w;    w += (size_t)NATOMS * sizeof(int);
  int*  cursor = (int*)w;

  hipMemsetAsync(cnt, 0, (size_t)NATOMS * sizeof(int), stream);

  hist_kernel<<<(NEDGES + 255) / 256, 256, 0, stream>>>(eix, cnt);
  scan_kernel<<<1, 512, 0, stream>>>(cnt, off);
  hipMemcpyAsync(cursor, off, (size_t)NATOMS * sizeof(int),
                 hipMemcpyDeviceToDevice, stream);
  scatter_kernel<<<(NEDGES + 255) / 256, 256, 0, stream>>>(eix, cursor, sorted);

  mlp_kernel<<<NATOMS / APB, 128, 0, stream>>>(q, W1, b1, W2, b2v, x);

  gather_kernel<<<NATOMS, 128, 0, stream>>>(q, mu, x, eix, ew, Wf, bfv,
                                            off, sorted, out);
}